// Round 18
// baseline (133.496 us; speedup 1.0000x reference)
//
#include <hip/hip_runtime.h>
#include <math.h>

static constexpr int BLK = 256;  // 4 waves
static constexpr int CH = 2048;  // scan-point chunk per block
static constexpr int SUB = 256;  // subtile staged in LDS (4 KB)
static constexpr int QB = 128;   // queries per block (32 per wave)

typedef _Float16 f16x8 __attribute__((ext_vector_type(8)));
typedef float f32x16 __attribute__((ext_vector_type(16)));

__device__ __forceinline__ unsigned f2u(float f) { return __float_as_uint(f); }
__device__ __forceinline__ float u2f(unsigned u) { return __uint_as_float(u); }
__device__ __forceinline__ unsigned pk(_Float16 a, _Float16 b) {
    union { _Float16 h[2]; unsigned u; } c; c.h[0] = a; c.h[1] = b; return c.u;
}
union B128 { uint4 u; f16x8 h; };

// prep: sentinels + out=0 (288 KB ws).
__global__ void prep_kernel(unsigned long long* __restrict__ o2s,
                            unsigned* __restrict__ s2o,
                            float* __restrict__ out, int N, int M) {
    int i = blockIdx.x * blockDim.x + threadIdx.x;
    if (i < N) o2s[i] = ~0ull;
    if (i < M) s2o[i] = 0xFFFFFFFFu;
    if (i == 0) out[0] = 0.0f;
}

// MFMA NN scan: m_ij = 0.5|s_j|^2 - p_i.s_j as a K=4 contraction padded into
// v_mfma_f32_32x32x16_f16 (1024 pairs / ~8cyc). A = 32 queries (-x,-y,-z,1),
// B = 32 scan points (x,y,z,w) from a 16B/point LDS tile; lanes>=32 feed zero
// k-slots (k = 8*(lane>>5)+reg is identical for A and B, so padding is safe).
// C/D layout (HW-measured, dtype-independent): col=lane&31,
// row=(reg&3)+8*(reg>>2)+4*(lane>>5).
// d2 = 2*(0.5|p|^2 + m), all coords f16-quantized consistently (R12/R13
// numerics passed). o2s packs the 6-bit tile-group into low mantissa bits
// during the sweep, repacks an 11-bit chunk-local index (tg*32+col) before
// the cross-lane butterfly so the argmin survives the lane reduction.
__global__ void __launch_bounds__(BLK) main_kernel(
    const float* __restrict__ P, const float* __restrict__ Ps,
    unsigned long long* __restrict__ o2s, unsigned* __restrict__ s2o,
    int N, int M, int o2sBlocks, int o2sRG, int s2oRG) {
    __shared__ uint4 lds16[SUB + 1];
    int tid = threadIdx.x;
    int lane = tid & 63, wave = tid >> 6;
    int n = lane & 31, half = lane >> 5;
    if (tid == 0) lds16[SUB] = make_uint4(0u, 0u, 0u, 0u);  // zero record

    int bx = blockIdx.x;
    bool isO2S = bx < o2sBlocks;
    const float* qsrc; const float* ssrc;
    int i0, j0, scnt;
    if (isO2S) {
        int rg = bx % o2sRG, c = bx / o2sRG;
        i0 = rg * QB + wave * 32; j0 = c * CH; scnt = M;
        qsrc = P; ssrc = Ps;                    // queries=P(N), scan=Ps(M)
    } else {
        int b = bx - o2sBlocks;
        int rg = b % s2oRG, c = b / s2oRG;
        i0 = rg * QB + wave * 32; j0 = c * CH; scnt = N;
        qsrc = Ps; ssrc = P;                    // queries=Ps(M), scan=P(N)
    }

    // A-frag: lane<32 holds query i0+n at k=0..3 = (-x,-y,-z,1); else zeros.
    f16x8 af;
    {
        float x = 0.f, y = 0.f, z = 0.f;
        if (half == 0) {
            int i = i0 + n;
            x = qsrc[3 * i]; y = qsrc[3 * i + 1]; z = qsrc[3 * i + 2];
        }
        _Float16 hx = (_Float16)x, hy = (_Float16)y, hz = (_Float16)z;
        _Float16 one = (half == 0) ? (_Float16)1.0f : (_Float16)0.0f;
        af = (f16x8){(_Float16)-hx, (_Float16)-hy, (_Float16)-hz, one,
                     (_Float16)0.0f, (_Float16)0.0f, (_Float16)0.0f, (_Float16)0.0f};
    }

    float runm[16];
#pragma unroll
    for (int r = 0; r < 16; ++r) runm[r] = __builtin_inff();
    f32x16 zacc = {};

    for (int s = 0; s < CH / SUB; ++s) {
        __syncthreads();
        {   // stage subtile: 1 point/thread, f16-packed (x,y,z,w=0.5|s|^2)
            int jj = j0 + s * SUB + tid;
            jj = min(jj, scnt - 1);  // defensive clamp (CH divides scnt exactly)
            float x = ssrc[3 * jj], y = ssrc[3 * jj + 1], z = ssrc[3 * jj + 2];
            _Float16 hx = (_Float16)x, hy = (_Float16)y, hz = (_Float16)z;
            float fx = (float)hx, fy = (float)hy, fz = (float)hz;
            _Float16 hw = (_Float16)(0.5f * (fx * fx + fy * fy + fz * fz));
            lds16[tid] = make_uint4(pk(hx, hy), pk(hz, hw), 0u, 0u);
        }
        __syncthreads();
#pragma unroll
        for (int t = 0; t < SUB / 32; ++t) {
            B128 bv;
            bv.u = lds16[half ? SUB : (t * 32 + n)];
            f32x16 cc = __builtin_amdgcn_mfma_f32_32x32x16_f16(af, bv.h, zacc, 0, 0, 0);
            unsigned tg = (unsigned)(s * 8 + t);
            if (isO2S) {
#pragma unroll
                for (int r = 0; r < 16; ++r)
                    runm[r] = fminf(runm[r], u2f((f2u(cc[r]) & ~63u) | tg));
            } else {
#pragma unroll
                for (int r = 0; r < 16; ++r)
                    runm[r] = fminf(runm[r], cc[r]);
            }
        }
    }

    if (isO2S) {  // repack 11-bit chunk-local index = tile-group*32 + col(lane)
#pragma unroll
        for (int r = 0; r < 16; ++r) {
            unsigned u = f2u(runm[r]);
            unsigned full = ((u & 63u) << 5) | (unsigned)n;
            runm[r] = u2f((u & ~0x7FFu) | full);
        }
    }
    // butterfly min within each 32-lane half (masks 1..16 stay inside a half)
#pragma unroll
    for (int mask = 1; mask < 32; mask <<= 1) {
#pragma unroll
        for (int r = 0; r < 16; ++r)
            runm[r] = fminf(runm[r], __shfl_xor(runm[r], mask, 64));
    }
    if (n < 16) {  // one writer lane per reg per half
        int r = n;
        int row = (r & 3) + 8 * (r >> 2) + 4 * half;
        int i = i0 + row;
        float x = qsrc[3 * i], y = qsrc[3 * i + 1], z = qsrc[3 * i + 2];
        _Float16 hx = (_Float16)x, hy = (_Float16)y, hz = (_Float16)z;
        float fx = (float)hx, fy = (float)hy, fz = (float)hz;
        float pw = 0.5f * (fx * fx + fy * fy + fz * fz);
        float v = runm[r];
        float d2 = fmaxf(2.0f * (pw + v), 0.0f);
        if (isO2S) {
            unsigned jloc = f2u(v) & 0x7FFu;
            unsigned long long key =
                ((unsigned long long)f2u(d2) << 32) | (unsigned)(j0 + (int)jloc);
            atomicMin(&o2s[i], key);
        } else {
            atomicMin(&s2o[i], f2u(d2));
        }
    }
}

// finish: one load per query, weight, block-reduce, one atomicAdd per block.
__global__ void finish_kernel(const unsigned* __restrict__ s2o,
                              const unsigned long long* __restrict__ o2s,
                              const float* __restrict__ prob,
                              float* __restrict__ out, int N, int M) {
    int t = blockIdx.x * BLK + threadIdx.x;
    float acc = 0.0f;
    if (t < M) {
        acc = sqrtf(u2f(s2o[t])) * prob[t];
    } else if (t < M + N) {
        unsigned long long key = o2s[t - M];
        float d2 = u2f((unsigned)(key >> 32));
        unsigned jj = (unsigned)(key & 0xFFFFFFFFu);
        acc = sqrtf(d2) * prob[jj];
    }
#pragma unroll
    for (int off = 32; off > 0; off >>= 1) acc += __shfl_down(acc, off, 64);
    __shared__ float wsum[BLK / 64];
    int lane = threadIdx.x & 63, wave = threadIdx.x >> 6;
    if (lane == 0) wsum[wave] = acc;
    __syncthreads();
    if (threadIdx.x == 0) {
        float s = 0.0f;
#pragma unroll
        for (int w = 0; w < BLK / 64; ++w) s += wsum[w];
        atomicAdd(out, s);
    }
}

extern "C" void kernel_launch(void* const* d_in, const int* in_sizes, int n_in,
                              void* d_out, int out_size, void* d_ws, size_t ws_size,
                              hipStream_t stream) {
    const float* P = (const float*)d_in[0];
    const float* Ps = (const float*)d_in[1];
    const float* prob = (const float*)d_in[2];
    int N = in_sizes[0] / 3;  // 32768
    int M = in_sizes[1] / 3;  // 8192
    float* out = (float*)d_out;

    unsigned long long* o2s = (unsigned long long*)d_ws;       // N * 8 B
    unsigned* s2o = (unsigned*)((char*)d_ws + (size_t)N * 8);  // M * 4 B

    int o2sRG = N / QB;                    // 256
    int s2oRG = M / QB;                    // 64
    int o2sBlocks = o2sRG * (M / CH);      // 256*4  = 1024
    int s2oBlocks = s2oRG * (N / CH);      // 64*16  = 1024
    int total = o2sBlocks + s2oBlocks;     // 2048 = 8 blocks/CU

    prep_kernel<<<(N + BLK - 1) / BLK, BLK, 0, stream>>>(o2s, s2o, out, N, M);
    main_kernel<<<total, BLK, 0, stream>>>(P, Ps, o2s, s2o, N, M,
                                           o2sBlocks, o2sRG, s2oRG);
    finish_kernel<<<(N + M + BLK - 1) / BLK, BLK, 0, stream>>>(s2o, o2s, prob,
                                                               out, N, M);
}

// Round 19
// 96.835 us; speedup vs baseline: 1.3786x; 1.3786x over previous
//
#include <hip/hip_runtime.h>
#include <math.h>

static constexpr int BLK = 256;  // 4 waves
static constexpr int CH = 2048;  // scan-point chunk per block
static constexpr int SUB = 256;  // subtile staged in LDS (4 KB)
static constexpr int QB = 128;   // queries per block (32 per wave)

typedef _Float16 f16x8 __attribute__((ext_vector_type(8)));
typedef float f32x16 __attribute__((ext_vector_type(16)));

__device__ __forceinline__ unsigned f2u(float f) { return __float_as_uint(f); }
__device__ __forceinline__ float u2f(unsigned u) { return __uint_as_float(u); }
__device__ __forceinline__ unsigned pk(_Float16 a, _Float16 b) {
    union { _Float16 h[2]; unsigned u; } c; c.h[0] = a; c.h[1] = b; return c.u;
}
union B128 { uint4 u; f16x8 h; };

// prep: sentinels + out=0 (288 KB ws).
__global__ void prep_kernel(unsigned long long* __restrict__ o2s,
                            unsigned* __restrict__ s2o,
                            float* __restrict__ out, int N, int M) {
    int i = blockIdx.x * blockDim.x + threadIdx.x;
    if (i < N) o2s[i] = ~0ull;
    if (i < M) s2o[i] = 0xFFFFFFFFu;
    if (i == 0) out[0] = 0.0f;
}

// MFMA NN scan (R18 verified correct; this round: pipeline it).
// R18 post-mortem: VGPR=44 -> single AGPR accumulator tuple -> MFMA->fold
// serialized on MFMA latency. waves_per_eu(4,4) gives 128-VGPR budget (pin
// respected per R16); 2 MFMAs per fold step (v_min3) halves fold issue and
// gives the scheduler two independent cc tuples to overlap.
__global__ void __launch_bounds__(BLK)
__attribute__((amdgpu_waves_per_eu(4, 4))) main_kernel(
    const float* __restrict__ P, const float* __restrict__ Ps,
    unsigned long long* __restrict__ o2s, unsigned* __restrict__ s2o,
    int N, int M, int o2sBlocks, int o2sRG, int s2oRG) {
    __shared__ uint4 lds16[SUB + 1];
    int tid = threadIdx.x;
    int lane = tid & 63, wave = tid >> 6;
    int n = lane & 31, half = lane >> 5;
    if (tid == 0) lds16[SUB] = make_uint4(0u, 0u, 0u, 0u);  // zero record

    int bx = blockIdx.x;
    bool isO2S = bx < o2sBlocks;
    const float* qsrc; const float* ssrc;
    int i0, j0, scnt;
    if (isO2S) {
        int rg = bx % o2sRG, c = bx / o2sRG;
        i0 = rg * QB + wave * 32; j0 = c * CH; scnt = M;
        qsrc = P; ssrc = Ps;                    // queries=P(N), scan=Ps(M)
    } else {
        int b = bx - o2sBlocks;
        int rg = b % s2oRG, c = b / s2oRG;
        i0 = rg * QB + wave * 32; j0 = c * CH; scnt = N;
        qsrc = Ps; ssrc = P;                    // queries=Ps(M), scan=P(N)
    }

    // A-frag: lane<32 holds query i0+n at k=0..3 = (-x,-y,-z,1); else zeros.
    f16x8 af;
    {
        float x = 0.f, y = 0.f, z = 0.f;
        if (half == 0) {
            int i = i0 + n;
            x = qsrc[3 * i]; y = qsrc[3 * i + 1]; z = qsrc[3 * i + 2];
        }
        _Float16 hx = (_Float16)x, hy = (_Float16)y, hz = (_Float16)z;
        _Float16 one = (half == 0) ? (_Float16)1.0f : (_Float16)0.0f;
        af = (f16x8){(_Float16)-hx, (_Float16)-hy, (_Float16)-hz, one,
                     (_Float16)0.0f, (_Float16)0.0f, (_Float16)0.0f, (_Float16)0.0f};
    }

    float runm[16];
#pragma unroll
    for (int r = 0; r < 16; ++r) runm[r] = __builtin_inff();
    f32x16 zacc = {};

    for (int s = 0; s < CH / SUB; ++s) {
        __syncthreads();
        {   // stage subtile: 1 point/thread, f16-packed (x,y,z,w=0.5|s|^2)
            int jj = j0 + s * SUB + tid;
            jj = min(jj, scnt - 1);  // defensive clamp (CH divides scnt exactly)
            float x = ssrc[3 * jj], y = ssrc[3 * jj + 1], z = ssrc[3 * jj + 2];
            _Float16 hx = (_Float16)x, hy = (_Float16)y, hz = (_Float16)z;
            float fx = (float)hx, fy = (float)hy, fz = (float)hz;
            _Float16 hw = (_Float16)(0.5f * (fx * fx + fy * fy + fz * fz));
            lds16[tid] = make_uint4(pk(hx, hy), pk(hz, hw), 0u, 0u);
        }
        __syncthreads();
        // 8 tile-groups per stage, processed 2 per fold step (independent
        // cc tuples -> MFMA t+1 overlaps fold t; v_min3 folds both at once).
#pragma unroll
        for (int t = 0; t < SUB / 32; t += 2) {
            B128 bva, bvb;
            bva.u = lds16[half ? SUB : (t * 32 + n)];
            bvb.u = lds16[half ? SUB : ((t + 1) * 32 + n)];
            f32x16 ca = __builtin_amdgcn_mfma_f32_32x32x16_f16(af, bva.h, zacc, 0, 0, 0);
            f32x16 cb = __builtin_amdgcn_mfma_f32_32x32x16_f16(af, bvb.h, zacc, 0, 0, 0);
            unsigned tga = (unsigned)(s * 8 + t), tgb = (unsigned)(s * 8 + t + 1);
            if (isO2S) {
#pragma unroll
                for (int r = 0; r < 16; ++r) {
                    float pa = u2f((f2u(ca[r]) & ~63u) | tga);
                    float pb = u2f((f2u(cb[r]) & ~63u) | tgb);
                    runm[r] = fminf(fminf(runm[r], pa), pb);  // v_min3_f32
                }
            } else {
#pragma unroll
                for (int r = 0; r < 16; ++r)
                    runm[r] = fminf(fminf(runm[r], ca[r]), cb[r]);  // v_min3_f32
            }
        }
    }

    if (isO2S) {  // repack 11-bit chunk-local index = tile-group*32 + col(lane)
#pragma unroll
        for (int r = 0; r < 16; ++r) {
            unsigned u = f2u(runm[r]);
            unsigned full = ((u & 63u) << 5) | (unsigned)n;
            runm[r] = u2f((u & ~0x7FFu) | full);
        }
    }
    // butterfly min within each 32-lane half (masks 1..16 stay inside a half)
#pragma unroll
    for (int mask = 1; mask < 32; mask <<= 1) {
#pragma unroll
        for (int r = 0; r < 16; ++r)
            runm[r] = fminf(runm[r], __shfl_xor(runm[r], mask, 64));
    }
    if (n < 16) {  // one writer lane per reg per half
        int r = n;
        int row = (r & 3) + 8 * (r >> 2) + 4 * half;
        int i = i0 + row;
        float x = qsrc[3 * i], y = qsrc[3 * i + 1], z = qsrc[3 * i + 2];
        _Float16 hx = (_Float16)x, hy = (_Float16)y, hz = (_Float16)z;
        float fx = (float)hx, fy = (float)hy, fz = (float)hz;
        float pw = 0.5f * (fx * fx + fy * fy + fz * fz);
        float v = runm[r];
        float d2 = fmaxf(2.0f * (pw + v), 0.0f);
        if (isO2S) {
            unsigned jloc = f2u(v) & 0x7FFu;
            unsigned long long key =
                ((unsigned long long)f2u(d2) << 32) | (unsigned)(j0 + (int)jloc);
            atomicMin(&o2s[i], key);
        } else {
            atomicMin(&s2o[i], f2u(d2));
        }
    }
}

// finish: one load per query, weight, block-reduce, one atomicAdd per block.
__global__ void finish_kernel(const unsigned* __restrict__ s2o,
                              const unsigned long long* __restrict__ o2s,
                              const float* __restrict__ prob,
                              float* __restrict__ out, int N, int M) {
    int t = blockIdx.x * BLK + threadIdx.x;
    float acc = 0.0f;
    if (t < M) {
        acc = sqrtf(u2f(s2o[t])) * prob[t];
    } else if (t < M + N) {
        unsigned long long key = o2s[t - M];
        float d2 = u2f((unsigned)(key >> 32));
        unsigned jj = (unsigned)(key & 0xFFFFFFFFu);
        acc = sqrtf(d2) * prob[jj];
    }
#pragma unroll
    for (int off = 32; off > 0; off >>= 1) acc += __shfl_down(acc, off, 64);
    __shared__ float wsum[BLK / 64];
    int lane = threadIdx.x & 63, wave = threadIdx.x >> 6;
    if (lane == 0) wsum[wave] = acc;
    __syncthreads();
    if (threadIdx.x == 0) {
        float s = 0.0f;
#pragma unroll
        for (int w = 0; w < BLK / 64; ++w) s += wsum[w];
        atomicAdd(out, s);
    }
}

extern "C" void kernel_launch(void* const* d_in, const int* in_sizes, int n_in,
                              void* d_out, int out_size, void* d_ws, size_t ws_size,
                              hipStream_t stream) {
    const float* P = (const float*)d_in[0];
    const float* Ps = (const float*)d_in[1];
    const float* prob = (const float*)d_in[2];
    int N = in_sizes[0] / 3;  // 32768
    int M = in_sizes[1] / 3;  // 8192
    float* out = (float*)d_out;

    unsigned long long* o2s = (unsigned long long*)d_ws;       // N * 8 B
    unsigned* s2o = (unsigned*)((char*)d_ws + (size_t)N * 8);  // M * 4 B

    int o2sRG = N / QB;                    // 256
    int s2oRG = M / QB;                    // 64
    int o2sBlocks = o2sRG * (M / CH);      // 256*4  = 1024
    int s2oBlocks = s2oRG * (N / CH);      // 64*16  = 1024
    int total = o2sBlocks + s2oBlocks;     // 2048 = 8 blocks/CU

    prep_kernel<<<(N + BLK - 1) / BLK, BLK, 0, stream>>>(o2s, s2o, out, N, M);
    main_kernel<<<total, BLK, 0, stream>>>(P, Ps, o2s, s2o, N, M,
                                           o2sBlocks, o2sRG, s2oRG);
    finish_kernel<<<(N + M + BLK - 1) / BLK, BLK, 0, stream>>>(s2o, o2s, prob,
                                                               out, N, M);
}

// Round 20
// 91.760 us; speedup vs baseline: 1.4548x; 1.0553x over previous
//
#include <hip/hip_runtime.h>
#include <math.h>

static constexpr int BLK = 256;  // 4 waves
static constexpr int CH = 2048;  // scan-point chunk per block (8 stages)
static constexpr int SUB = 256;  // subtile staged in LDS (4 KB)
static constexpr int QB = 128;   // queries per block (32 per wave)

typedef _Float16 f16x8 __attribute__((ext_vector_type(8)));
typedef float f32x16 __attribute__((ext_vector_type(16)));

__device__ __forceinline__ unsigned f2u(float f) { return __float_as_uint(f); }
__device__ __forceinline__ float u2f(unsigned u) { return __uint_as_float(u); }
__device__ __forceinline__ unsigned pk(_Float16 a, _Float16 b) {
    union { _Float16 h[2]; unsigned u; } c; c.h[0] = a; c.h[1] = b; return c.u;
}
union B128 { uint4 u; f16x8 h; };

// prep: sentinels + out=0 (288 KB ws).
__global__ void prep_kernel(unsigned long long* __restrict__ o2s,
                            unsigned* __restrict__ s2o,
                            float* __restrict__ out, int N, int M) {
    int i = blockIdx.x * blockDim.x + threadIdx.x;
    if (i < N) o2s[i] = ~0ull;
    if (i < M) s2o[i] = 0xFFFFFFFFu;
    if (i == 0) out[0] = 0.0f;
}

// MFMA NN scan, depth-4 ILP + stage-granular argmin tags.
// R19 (depth-2): main 42.6us, latency-bound (no pipe >60%). This round:
// 4 independent cc tuples per fold group (64 VGPRs; waves_per_eu(4,4) budget
// 128) and o2s fold cut 24->12 inst/MFMA: pure v_min3 inside a 256-pt stage,
// one 3-bit stage tag per stage; exact argmin recovered in the epilogue by
// rescanning the winning stage's 8 candidates (known col) with scalar math.
__global__ void __launch_bounds__(BLK)
__attribute__((amdgpu_waves_per_eu(4, 4))) main_kernel(
    const float* __restrict__ P, const float* __restrict__ Ps,
    unsigned long long* __restrict__ o2s, unsigned* __restrict__ s2o,
    int N, int M, int o2sBlocks, int o2sRG, int s2oRG) {
    __shared__ uint4 lds16[SUB + 1];
    int tid = threadIdx.x;
    int lane = tid & 63, wave = tid >> 6;
    int n = lane & 31, half = lane >> 5;
    if (tid == 0) lds16[SUB] = make_uint4(0u, 0u, 0u, 0u);  // zero record

    int bx = blockIdx.x;
    bool isO2S = bx < o2sBlocks;
    const float* qsrc; const float* ssrc;
    int i0, j0, scnt;
    if (isO2S) {
        int rg = bx % o2sRG, c = bx / o2sRG;
        i0 = rg * QB + wave * 32; j0 = c * CH; scnt = M;
        qsrc = P; ssrc = Ps;                    // queries=P(N), scan=Ps(M)
    } else {
        int b = bx - o2sBlocks;
        int rg = b % s2oRG, c = b / s2oRG;
        i0 = rg * QB + wave * 32; j0 = c * CH; scnt = N;
        qsrc = Ps; ssrc = P;                    // queries=Ps(M), scan=P(N)
    }

    // A-frag: lane<32 holds query i0+n at k=0..3 = (-x,-y,-z,1); else zeros.
    f16x8 af;
    {
        float x = 0.f, y = 0.f, z = 0.f;
        if (half == 0) {
            int i = i0 + n;
            x = qsrc[3 * i]; y = qsrc[3 * i + 1]; z = qsrc[3 * i + 2];
        }
        _Float16 hx = (_Float16)x, hy = (_Float16)y, hz = (_Float16)z;
        _Float16 one = (half == 0) ? (_Float16)1.0f : (_Float16)0.0f;
        af = (f16x8){(_Float16)-hx, (_Float16)-hy, (_Float16)-hz, one,
                     (_Float16)0.0f, (_Float16)0.0f, (_Float16)0.0f, (_Float16)0.0f};
    }

    float runm[16];
#pragma unroll
    for (int r = 0; r < 16; ++r) runm[r] = __builtin_inff();
    f32x16 zacc = {};

    for (int s = 0; s < CH / SUB; ++s) {
        __syncthreads();
        {   // stage subtile: 1 point/thread, f16-packed (x,y,z,w=0.5|s|^2)
            int jj = j0 + s * SUB + tid;
            jj = min(jj, scnt - 1);  // defensive clamp (CH divides scnt exactly)
            float x = ssrc[3 * jj], y = ssrc[3 * jj + 1], z = ssrc[3 * jj + 2];
            _Float16 hx = (_Float16)x, hy = (_Float16)y, hz = (_Float16)z;
            float fx = (float)hx, fy = (float)hy, fz = (float)hz;
            _Float16 hw = (_Float16)(0.5f * (fx * fx + fy * fy + fz * fz));
            lds16[tid] = make_uint4(pk(hx, hy), pk(hz, hw), 0u, 0u);
        }
        __syncthreads();
        float smin[16];
#pragma unroll
        for (int r = 0; r < 16; ++r) smin[r] = __builtin_inff();
        // 8 tile-groups per stage, 4 MFMAs in flight per fold group; pure
        // min3 folds (no per-MFMA tags).
#pragma unroll
        for (int t = 0; t < SUB / 32; t += 4) {
            B128 b0, b1, b2, b3;
            b0.u = lds16[half ? SUB : ((t + 0) * 32 + n)];
            b1.u = lds16[half ? SUB : ((t + 1) * 32 + n)];
            b2.u = lds16[half ? SUB : ((t + 2) * 32 + n)];
            b3.u = lds16[half ? SUB : ((t + 3) * 32 + n)];
            f32x16 c0 = __builtin_amdgcn_mfma_f32_32x32x16_f16(af, b0.h, zacc, 0, 0, 0);
            f32x16 c1 = __builtin_amdgcn_mfma_f32_32x32x16_f16(af, b1.h, zacc, 0, 0, 0);
            f32x16 c2 = __builtin_amdgcn_mfma_f32_32x32x16_f16(af, b2.h, zacc, 0, 0, 0);
            f32x16 c3 = __builtin_amdgcn_mfma_f32_32x32x16_f16(af, b3.h, zacc, 0, 0, 0);
#pragma unroll
            for (int r = 0; r < 16; ++r) {
                smin[r] = fminf(fminf(smin[r], c0[r]), c1[r]);  // v_min3
                smin[r] = fminf(fminf(smin[r], c2[r]), c3[r]);  // v_min3
            }
        }
        // stage merge: tag with 3-bit stage id (o2s) or plain min (s2o)
        if (isO2S) {
#pragma unroll
            for (int r = 0; r < 16; ++r)
                runm[r] = fminf(runm[r], u2f((f2u(smin[r]) & ~0xFFu) | (unsigned)s));
        } else {
#pragma unroll
            for (int r = 0; r < 16; ++r)
                runm[r] = fminf(runm[r], smin[r]);
        }
    }

    if (isO2S) {  // repack low 8 bits: (stage<<5)|col so argmin survives lanes
#pragma unroll
        for (int r = 0; r < 16; ++r) {
            unsigned u = f2u(runm[r]);
            runm[r] = u2f((u & ~0xFFu) | ((u & 7u) << 5) | (unsigned)n);
        }
    }
    // butterfly min within each 32-lane half (masks 1..16 stay inside a half)
#pragma unroll
    for (int mask = 1; mask < 32; mask <<= 1) {
#pragma unroll
        for (int r = 0; r < 16; ++r)
            runm[r] = fminf(runm[r], __shfl_xor(runm[r], mask, 64));
    }
    if (n < 16) {  // one writer lane per reg per half
        int r = n;
        int row = (r & 3) + 8 * (r >> 2) + 4 * half;
        int i = i0 + row;
        float x = qsrc[3 * i], y = qsrc[3 * i + 1], z = qsrc[3 * i + 2];
        _Float16 hx = (_Float16)x, hy = (_Float16)y, hz = (_Float16)z;
        float fx = (float)hx, fy = (float)hy, fz = (float)hz;
        float nx = -fx, ny = -fy, nz = -fz;
        float pw = 0.5f * (fx * fx + fy * fy + fz * fz);
        if (isO2S) {
            // recover exact argmin: rescan the winning stage's 8 candidates
            unsigned uv = f2u(runm[r]);
            int sWin = (int)((uv >> 5) & 7u);
            int col = (int)(uv & 31u);
            float best = __builtin_inff();
            int bj = 0;
#pragma unroll
            for (int t = 0; t < 8; ++t) {
                int j = j0 + sWin * SUB + t * 32 + col;
                float sx = (float)(_Float16)ssrc[3 * j];
                float sy = (float)(_Float16)ssrc[3 * j + 1];
                float sz = (float)(_Float16)ssrc[3 * j + 2];
                float sw = 0.5f * (sx * sx + sy * sy + sz * sz);
                float m = fmaf(sx, nx, fmaf(sy, ny, fmaf(sz, nz, sw)));
                if (m < best) { best = m; bj = j; }
            }
            float d2 = fmaxf(2.0f * (pw + best), 0.0f);
            unsigned long long key =
                ((unsigned long long)f2u(d2) << 32) | (unsigned)bj;
            atomicMin(&o2s[i], key);
        } else {
            float d2 = fmaxf(2.0f * (pw + runm[r]), 0.0f);
            atomicMin(&s2o[i], f2u(d2));
        }
    }
}

// finish: one load per query, weight, block-reduce, one atomicAdd per block.
__global__ void finish_kernel(const unsigned* __restrict__ s2o,
                              const unsigned long long* __restrict__ o2s,
                              const float* __restrict__ prob,
                              float* __restrict__ out, int N, int M) {
    int t = blockIdx.x * BLK + threadIdx.x;
    float acc = 0.0f;
    if (t < M) {
        acc = sqrtf(u2f(s2o[t])) * prob[t];
    } else if (t < M + N) {
        unsigned long long key = o2s[t - M];
        float d2 = u2f((unsigned)(key >> 32));
        unsigned jj = (unsigned)(key & 0xFFFFFFFFu);
        acc = sqrtf(d2) * prob[jj];
    }
#pragma unroll
    for (int off = 32; off > 0; off >>= 1) acc += __shfl_down(acc, off, 64);
    __shared__ float wsum[BLK / 64];
    int lane = threadIdx.x & 63, wave = threadIdx.x >> 6;
    if (lane == 0) wsum[wave] = acc;
    __syncthreads();
    if (threadIdx.x == 0) {
        float s = 0.0f;
#pragma unroll
        for (int w = 0; w < BLK / 64; ++w) s += wsum[w];
        atomicAdd(out, s);
    }
}

extern "C" void kernel_launch(void* const* d_in, const int* in_sizes, int n_in,
                              void* d_out, int out_size, void* d_ws, size_t ws_size,
                              hipStream_t stream) {
    const float* P = (const float*)d_in[0];
    const float* Ps = (const float*)d_in[1];
    const float* prob = (const float*)d_in[2];
    int N = in_sizes[0] / 3;  // 32768
    int M = in_sizes[1] / 3;  // 8192
    float* out = (float*)d_out;

    unsigned long long* o2s = (unsigned long long*)d_ws;       // N * 8 B
    unsigned* s2o = (unsigned*)((char*)d_ws + (size_t)N * 8);  // M * 4 B

    int o2sRG = N / QB;                    // 256
    int s2oRG = M / QB;                    // 64
    int o2sBlocks = o2sRG * (M / CH);      // 256*4  = 1024
    int s2oBlocks = s2oRG * (N / CH);      // 64*16  = 1024
    int total = o2sBlocks + s2oBlocks;     // 2048 = 8 blocks/CU

    prep_kernel<<<(N + BLK - 1) / BLK, BLK, 0, stream>>>(o2s, s2o, out, N, M);
    main_kernel<<<total, BLK, 0, stream>>>(P, Ps, o2s, s2o, N, M,
                                           o2sBlocks, o2sRG, s2oRG);
    finish_kernel<<<(N + M + BLK - 1) / BLK, BLK, 0, stream>>>(s2o, o2s, prob,
                                                               out, N, M);
}